// Round 3
// baseline (585.564 us; speedup 1.0000x reference)
//
#include <hip/hip_runtime.h>

#define D_MODEL 2048
#define SEQ     2048
#define BATCH   4
#define MTOT    (BATCH * SEQ)   // 8192
#define NQKV    (3 * D_MODEL)   // 6144

typedef __attribute__((ext_vector_type(8))) short bf16x8;
typedef __attribute__((ext_vector_type(8))) unsigned short ushort8;
typedef __attribute__((ext_vector_type(4))) float floatx4;

__device__ __forceinline__ unsigned short f2b(float f) {
    unsigned x = __builtin_bit_cast(unsigned, f);
    x += 0x7fffu + ((x >> 16) & 1u);   // round-to-nearest-even
    return (unsigned short)(x >> 16);
}

__device__ __forceinline__ void storeC(float* p, float v) { *p = v; }
__device__ __forceinline__ void storeC(unsigned short* p, float v) { *p = f2b(v); }

__device__ __forceinline__ void gload_lds16(const void* g, void* l) {
    __builtin_amdgcn_global_load_lds(
        (const __attribute__((address_space(1))) void*)g,
        (__attribute__((address_space(3))) void*)l,
        16, 0, 0);
}

// ---------------------------------------------------------------------------
// 256x256 BT GEMM, 8-phase/K-tile with ONE-PHASE READ-AHEAD (z-batched):
// C[m,n] = sum_k A[m,k]*B[n,k] (+bias)(*scale). A,B bf16 k-major. BK=64,
// 8 waves (2M x 4N), per-wave C = 128x64.
// Phase (q,ks): 8 mfma_16x16x32 on frags read in the PREVIOUS phase
// (ping-pong afA/afB; bfA=ks0 / bfB=ks1 per 4-phase half), so ds_read latency
// hides under MFMA via compiler-counted lgkmcnt (never a forced drain).
// Staging: 1 granule (64 LDS rows = 8KB, one global_load_lds per wave) per
// phase, placed >=1 barrier after the last read of the region it overwrites:
//   P0: A1g1(kt+1)->O | P4: Bg0,Bg1(kt+2)->S | P5: Bg2,A0g0(kt+2)->S
//   P6: Bg3,A0g1(kt+2)->S | P7: A1g0(kt+2)->S
// vmcnt placement rule (R2 NaN post-mortem): a wave's vmcnt covers only ITS
// OWN loads, but frag reads consume rows staged by all 8 waves. The wait MUST
// be producer-side: vmcnt BEFORE the barrier that precedes the consuming
// phase. Steady: vmcnt(8) at P0-end [A1(kt) landed -> P1/P2/P5/P6 reads],
// vmcnt(8) at P6-end [B(kt+1)+A0(kt+1) landed -> P7 prefetch reads].
// Prologue: stage tiles 0,1 (15 gloads), vmcnt(7), BARRIER, then tile-0 reads.
// Tails: P0-end vmcnt(8)/vmcnt(0); P6-end vmcnt(2). Counts verified by issue
// simulation (8 issues/K-tile steady; 4 half-tiles in flight).
// Requires NK even, NK >= 6 (all call sites: K=2048, NK=32).
// NOTE: default raster, no XCD swizzle (R4: swizzle tripled FETCH here).
// ---------------------------------------------------------------------------
#define BAR() do { asm volatile("" ::: "memory");                             \
                   __builtin_amdgcn_s_barrier();                              \
                   asm volatile("" ::: "memory"); } while (0)
#define VMW(N) asm volatile("s_waitcnt vmcnt(" #N ")" ::: "memory")

#define MFMA8(q, AF, BF)                                                      \
    __builtin_amdgcn_s_setprio(1);                                            \
    _Pragma("unroll") for (int mi = 0; mi < 2; ++mi)                          \
    _Pragma("unroll") for (int ni = 0; ni < 4; ++ni)                          \
        acc[(q) * 2 + mi][ni] = __builtin_amdgcn_mfma_f32_16x16x32_bf16(      \
            AF[mi], BF[ni], acc[(q) * 2 + mi][ni], 0, 0, 0);                  \
    __builtin_amdgcn_s_setprio(0);

// M: 0 = steady, 1 = tail1 (kt = NK-2), 2 = tail2 (kt = NK-1)
#define KTILE(KT, S, O, M)                                                    \
  {                                                                           \
    /* P0: q0ks0 */                                                           \
    ldAF(afB, &As[S][0][0], 1, cA0);                                          \
    if (M < 2) stA((KT) + 1, 1, 1, O);                                        \
    MFMA8(0, afA, bfA)                                                        \
    if (M == 2) { VMW(0); } else { VMW(8); }    /* A1(kt) landed */           \
    BAR();                                                                    \
    /* P1: q1ks0 */                                                           \
    ldAF(afA, &As[S][1][0], 0, cA0);                                          \
    MFMA8(1, afB, bfA) BAR();                                                 \
    /* P2: q2ks0 */                                                           \
    ldAF(afB, &As[S][1][0], 1, cA0);                                          \
    MFMA8(2, afA, bfA) BAR();                                                 \
    /* P3: q3ks0 */                                                           \
    ldAF(afA, &As[S][0][0], 0, cA1);                                          \
    ldBF(bfB, &Bs[S][wg_n >> 1][0], cA1);                                     \
    MFMA8(3, afB, bfA) BAR();                                                 \
    /* P4: q0ks1 */                                                           \
    ldAF(afB, &As[S][0][0], 1, cA1);                                          \
    if (M == 0) { stB((KT) + 2, 0, 0, S); stB((KT) + 2, 0, 1, S); }           \
    MFMA8(0, afA, bfB) BAR();                                                 \
    /* P5: q1ks1 */                                                           \
    ldAF(afA, &As[S][1][0], 0, cA1);                                          \
    if (M == 0) { stB((KT) + 2, 1, 0, S); stA((KT) + 2, 0, 0, S); }           \
    MFMA8(1, afB, bfB) BAR();                                                 \
    /* P6: q2ks1 */                                                           \
    ldAF(afB, &As[S][1][0], 1, cA1);                                          \
    if (M == 0) { stB((KT) + 2, 1, 1, S); stA((KT) + 2, 0, 1, S); }           \
    MFMA8(2, afA, bfB)                                                        \
    if (M == 0) { VMW(8); } else if (M == 1) { VMW(2); }  /* B,A0(kt+1) */    \
    BAR();                                                                    \
    /* P7: q3ks1 + next-tile ks0 prefetch-reads */                            \
    if (M < 2) {                                                              \
        ldAF(afA, &As[O][0][0], 0, cA0);                                      \
        ldBF(bfA, &Bs[O][wg_n >> 1][0], cA0);                                 \
    }                                                                         \
    if (M == 0) { stA((KT) + 2, 1, 0, S); }                                   \
    MFMA8(3, afB, bfB)                                                        \
    if (M < 2) BAR();                                                         \
  }

template <int EPI, typename CT>
__global__ __launch_bounds__(512, 2) void gemm256(
    const unsigned short* __restrict__ A, int lda, long long strA,
    const unsigned short* __restrict__ B, int ldb, long long strB,
    CT* __restrict__ C, int ldc, long long strC,
    int K, const float* __restrict__ bias, float scale)
{
    // [slot][half][128 rows x 64 k] each; 64 KiB A + 64 KiB B = 128 KiB
    __shared__ __align__(16) unsigned short As[2][2][128 * 64];
    __shared__ __align__(16) unsigned short Bs[2][2][128 * 64];

    const int t = threadIdx.x;
    const int w = t >> 6, l = t & 63;
    const int wg_m = w >> 2, wg_n = w & 3;       // 2 x 4 wave grid
    const int quad = l >> 4, r16 = l & 15, sw = l & 7;
    const int cA0 = (quad ^ sw) * 8;             // ks0 swizzled col (elems)
    const int cA1 = ((4 + quad) ^ sw) * 8;       // ks1

    const int bz = blockIdx.z;
    A += (long long)bz * strA;
    B += (long long)bz * strB;
    C += (long long)bz * strC;

    const long long tM = (long long)blockIdx.y * 256;
    const long long tN = (long long)blockIdx.x * 256;

    // staging: thread t -> granule row r0 = t>>3 (0..63), slot s = t&7.
    // LDS(r,s) holds global k-chunk s^(r&7) (involution swizzle).
    const int r0 = t >> 3;
    const int kx = ((t & 7) ^ (r0 & 7)) * 8;
    const unsigned short* gA = A + (tM + r0) * (long long)lda + kx;
    const unsigned short* gB = B + (tN + r0) * (long long)ldb + kx;

    // one granule (64 LDS rows) per call; wave w writes rows [w*8, w*8+8)
    auto stA = [&](int kt, int h, int g, int sl) {
        gload_lds16(gA + (long long)(g * 128 + h * 64) * lda + kt * 64,
                    &As[sl][h][g * 4096 + w * 512]);
    };
    auto stB = [&](int kt, int h, int g, int sl) {
        gload_lds16(gB + (long long)(h * 128 + g * 64) * ldb + kt * 64,
                    &Bs[sl][h][g * 4096 + w * 512]);
    };

    bf16x8 afA[2], afB[2], bfA[4], bfB[4];
    auto ldAF = [&](bf16x8 (&d)[2], const unsigned short* base, int rq, int col) {
#pragma unroll
        for (int mi = 0; mi < 2; ++mi)
            d[mi] = *(const bf16x8*)
                &base[(wg_m * 64 + rq * 32 + mi * 16 + r16) * 64 + col];
    };
    auto ldBF = [&](bf16x8 (&d)[4], const unsigned short* base, int col) {
#pragma unroll
        for (int ni = 0; ni < 4; ++ni)
            d[ni] = *(const bf16x8*)
                &base[((wg_n & 1) * 64 + ni * 16 + r16) * 64 + col];
    };

    floatx4 acc[8][4];
#pragma unroll
    for (int i = 0; i < 8; ++i)
#pragma unroll
        for (int j = 0; j < 4; ++j)
            acc[i][j] = (floatx4){0.f, 0.f, 0.f, 0.f};

    const int NK = K >> 6;   // even, >= 6 at all call sites

    // prologue: tile 0 (8 granules) then tile 1 (B, A0, A1g0 = 7 granules)
    stB(0, 0, 0, 0); stB(0, 0, 1, 0); stB(0, 1, 0, 0); stB(0, 1, 1, 0);
    stA(0, 0, 0, 0); stA(0, 0, 1, 0); stA(0, 1, 0, 0); stA(0, 1, 1, 0);
    stB(1, 0, 0, 1); stB(1, 0, 1, 1); stB(1, 1, 0, 1); stB(1, 1, 1, 1);
    stA(1, 0, 0, 1); stA(1, 0, 1, 1); stA(1, 1, 0, 1);
    VMW(7);                                   // MY tile-0 loads landed
    BAR();                                    // => ALL waves' tile-0 landed
    ldAF(afA, &As[0][0][0], 0, cA0);          // A(0, ks0, q0)
    ldBF(bfA, &Bs[0][wg_n >> 1][0], cA0);     // B(0, ks0)

    int kt = 0;
    for (; kt + 4 <= NK; kt += 2) {           // steady: kt = 0 .. NK-4
        KTILE(kt, 0, 1, 0)
        KTILE(kt + 1, 1, 0, 0)
    }
    KTILE(NK - 2, 0, 1, 1)                    // tail1
    KTILE(NK - 1, 1, 0, 2)                    // tail2 (no barrier after)

    // C/D layout: col = lane&15, row = (lane>>4)*4 + reg
#pragma unroll
    for (int mi = 0; mi < 8; ++mi) {
#pragma unroll
        for (int ni = 0; ni < 4; ++ni) {
            const long long row = tM + wg_m * 128 + mi * 16 + quad * 4;
            const int col = (int)tN + wg_n * 64 + ni * 16 + r16;
            float badd = 0.f;
            if (EPI == 0) badd = bias[col];
#pragma unroll
            for (int r = 0; r < 4; ++r) {
                float v = acc[mi][ni][r] + badd;
                if (EPI == 1) v *= scale;
                storeC(&C[(row + r) * ldc + col], v);
            }
        }
    }
}

// f32 -> bf16 bulk convert, 8 elems/thread (n divisible by 2048)
__global__ void cvt_f32_bf16(const float* __restrict__ in,
                             unsigned short* __restrict__ out, long long n)
{
    long long i = ((long long)blockIdx.x * 256 + threadIdx.x) * 8;
    if (i + 7 < n) {
        float4 a = *(const float4*)(in + i);
        float4 b = *(const float4*)(in + i + 4);
        ushort8 o = {f2b(a.x), f2b(a.y), f2b(a.z), f2b(a.w),
                     f2b(b.x), f2b(b.y), f2b(b.z), f2b(b.w)};
        *(ushort8*)(out + i) = o;
    }
}

// W_qkv f32 [2048, 6144] (f = 3*d + sel fastest) -> Wqkv_t bf16 [6144, 2048],
// Wqkv_t[sel*2048 + d][k] = W_qkv[k][3*d + sel].  Tile: 64 k x 32 d (96 cols).
__global__ void deint_wqkv(const float* __restrict__ W,
                           unsigned short* __restrict__ Wt)
{
    __shared__ unsigned short t2[96][72];   // row stride 144B (16B-aligned)
    const int d0 = blockIdx.x * 32;
    const int k0 = blockIdx.y * 64;
    const int t = threadIdx.x;

#pragma unroll
    for (int it = 0; it < 24; ++it) {
        int i = t + it * 256;               // 0..6143 over 64 rows x 96 cols
        int r = i / 96, c = i - r * 96;
        t2[c][r] = f2b(W[(long long)(k0 + r) * NQKV + 3 * d0 + c]);
    }
    __syncthreads();

#pragma unroll
    for (int rnd = 0; rnd < 3; ++rnd) {
        int c  = (t >> 3) + rnd * 32;       // 0..95
        int kc = t & 7;
        int dx = c / 3, sel = c - 3 * dx;
        *(ushort8*)&Wt[(long long)(sel * 2048 + d0 + dx) * D_MODEL + k0 + kc * 8] =
            *(const ushort8*)&t2[c][kc * 8];
    }
}

// W_fc f32 [2048, 2048] -> Wfc_t bf16, Wfc_t[n][k] = W_fc[k][n]. Tile 64x64.
__global__ void transpose_wfc(const float* __restrict__ W,
                              unsigned short* __restrict__ Wt)
{
    __shared__ unsigned short t2[64][72];
    const int n0 = blockIdx.x * 64;
    const int k0 = blockIdx.y * 64;
    const int t = threadIdx.x;

#pragma unroll
    for (int it = 0; it < 16; ++it) {
        int i = t + it * 256;               // 64 rows x 64 cols
        int r = i >> 6, c = i & 63;
        t2[c][r] = f2b(W[(long long)(k0 + r) * D_MODEL + n0 + c]);
    }
    __syncthreads();

#pragma unroll
    for (int rnd = 0; rnd < 2; ++rnd) {
        int c  = (t >> 3) + rnd * 32;
        int kc = t & 7;
        *(ushort8*)&Wt[(long long)(n0 + c) * D_MODEL + k0 + kc * 8] =
            *(const ushort8*)&t2[c][kc * 8];
    }
}

// bias deinterleave (f32 -> f32): bias_qkv_t[sel*2048+d] = bqkv[3*d+sel]
__global__ void prep_bias(const float* __restrict__ bqkv,
                          const float* __restrict__ bfc,
                          float* __restrict__ bias_qkv_t,
                          float* __restrict__ bias_fc)
{
    int i = blockIdx.x * 256 + threadIdx.x;
    if (i < NQKV) {
        int sel = i >> 11, d = i & 2047;
        bias_qkv_t[i] = bqkv[3 * d + sel];
    } else if (i < NQKV + D_MODEL) {
        bias_fc[i - NQKV] = bfc[i - NQKV];
    }
}

extern "C" void kernel_launch(void* const* d_in, const int* in_sizes, int n_in,
                              void* d_out, int out_size, void* d_ws, size_t ws_size,
                              hipStream_t stream)
{
    (void)in_sizes; (void)n_in; (void)out_size;

    const float* x    = (const float*)d_in[0];
    const float* Wqkv = (const float*)d_in[1];
    const float* bqkv = (const float*)d_in[2];
    const float* Wfc  = (const float*)d_in[3];
    const float* bfc  = (const float*)d_in[4];
    float* out = (float*)d_out;

    char* ws = (char*)d_ws;
    size_t off = 0;
    auto alloc = [&](size_t bytes) {
        void* p = ws + off;
        off += (bytes + 255) & ~(size_t)255;
        return p;
    };

    const float scale = 0.02209708691207961f;  // 2048^-0.5
    const long long nx = (long long)MTOT * D_MODEL;  // 16.8M elems

    const size_t NEED_BATCHED = (size_t)(33554432ull + 8388608ull + 25165824ull
                                + 100663296ull + 33554432ull + 65536ull);

    if (ws_size >= NEED_BATCHED) {
        unsigned short* xb     = (unsigned short*)alloc((size_t)MTOT * D_MODEL * 2);
        unsigned short* Wfc_t  = (unsigned short*)alloc((size_t)D_MODEL * D_MODEL * 2);
        unsigned short* Wqkv_t = (unsigned short*)alloc((size_t)NQKV * D_MODEL * 2);
        unsigned short* QKV    = (unsigned short*)alloc((size_t)MTOT * NQKV * 2);
        unsigned short* S      = (unsigned short*)alloc((size_t)BATCH * SEQ * SEQ * 2);
        float* bias_qkv = (float*)alloc((size_t)NQKV * 4);
        float* bias_fc  = (float*)alloc((size_t)D_MODEL * 4);
        unsigned short* Abuf = xb;   // xb dead after stage 1

        cvt_f32_bf16<<<(int)(nx / 2048), 256, 0, stream>>>(x, xb, nx);
        deint_wqkv<<<dim3(64, 32), 256, 0, stream>>>(Wqkv, Wqkv_t);
        transpose_wfc<<<dim3(32, 32), 256, 0, stream>>>(Wfc, Wfc_t);
        prep_bias<<<32, 256, 0, stream>>>(bqkv, bfc, bias_qkv, bias_fc);

        const long long sQKV = (long long)SEQ * NQKV;
        const long long sS   = (long long)SEQ * SEQ;

        // 1) QKV = xb @ Wqkv_t^T + bias   [8192 x 6144]
        gemm256<0, unsigned short><<<dim3(NQKV / 256, MTOT / 256, 1), 512, 0, stream>>>(
            xb, D_MODEL, 0, Wqkv_t, D_MODEL, 0, QKV, NQKV, 0, D_MODEL, bias_qkv, 1.f);
        // 2) S_b = Q_b @ K_b^T * scale    z-batched [2048 x 2048] x4
        gemm256<1, unsigned short><<<dim3(SEQ / 256, SEQ / 256, BATCH), 512, 0, stream>>>(
            QKV, NQKV, sQKV, QKV + D_MODEL, NQKV, sQKV, S, SEQ, sS, D_MODEL, nullptr, scale);
        // 3) A_b = S_b @ V_b^T            z-batched [2048 x 2048] x4
        gemm256<2, unsigned short><<<dim3(SEQ / 256, SEQ / 256, BATCH), 512, 0, stream>>>(
            S, SEQ, sS, QKV + 2 * D_MODEL, NQKV, sQKV, Abuf, SEQ, sS, SEQ, nullptr, 1.f);
        // 4) out = A @ Wfc_t^T + bias_fc  [8192 x 2048] f32 out
        gemm256<0, float><<<dim3(D_MODEL / 256, MTOT / 256, 1), 512, 0, stream>>>(
            Abuf, SEQ, 0, Wfc_t, D_MODEL, 0, out, D_MODEL, 0, SEQ, bias_fc, 1.f);
    } else {
        // Fallback: per-batch (~110 MB)
        unsigned short* xb     = (unsigned short*)alloc((size_t)MTOT * D_MODEL * 2);
        unsigned short* Wqkv_t = (unsigned short*)alloc((size_t)NQKV * D_MODEL * 2);
        unsigned short* Wfc_t  = (unsigned short*)alloc((size_t)D_MODEL * D_MODEL * 2);
        unsigned short* QKVb   = (unsigned short*)alloc((size_t)SEQ * NQKV * 2);
        unsigned short* Sb     = (unsigned short*)alloc((size_t)SEQ * SEQ * 2);
        unsigned short* Ab     = (unsigned short*)alloc((size_t)SEQ * SEQ * 2);
        float* bias_qkv = (float*)alloc((size_t)NQKV * 4);
        float* bias_fc  = (float*)alloc((size_t)D_MODEL * 4);

        cvt_f32_bf16<<<(int)(nx / 2048), 256, 0, stream>>>(x, xb, nx);
        deint_wqkv<<<dim3(64, 32), 256, 0, stream>>>(Wqkv, Wqkv_t);
        transpose_wfc<<<dim3(32, 32), 256, 0, stream>>>(Wfc, Wfc_t);
        prep_bias<<<32, 256, 0, stream>>>(bqkv, bfc, bias_qkv, bias_fc);

        for (int b = 0; b < BATCH; ++b) {
            const unsigned short* xb_b = xb + (long long)b * SEQ * D_MODEL;
            float* out_b = out + (long long)b * SEQ * D_MODEL;
            gemm256<0, unsigned short><<<dim3(NQKV / 256, SEQ / 256, 1), 512, 0, stream>>>(
                xb_b, D_MODEL, 0, Wqkv_t, D_MODEL, 0, QKVb, NQKV, 0, D_MODEL, bias_qkv, 1.f);
            gemm256<1, unsigned short><<<dim3(SEQ / 256, SEQ / 256, 1), 512, 0, stream>>>(
                QKVb, NQKV, 0, QKVb + D_MODEL, NQKV, 0, Sb, SEQ, 0, D_MODEL, nullptr, scale);
            gemm256<2, unsigned short><<<dim3(SEQ / 256, SEQ / 256, 1), 512, 0, stream>>>(
                Sb, SEQ, 0, QKVb + 2 * D_MODEL, NQKV, 0, Ab, SEQ, 0, SEQ, nullptr, 1.f);
            gemm256<0, float><<<dim3(D_MODEL / 256, SEQ / 256, 1), 512, 0, stream>>>(
                Ab, SEQ, 0, Wfc_t, D_MODEL, 0, out_b, D_MODEL, 0, SEQ, bias_fc, 1.f);
        }
    }
}

// Round 4
// 539.309 us; speedup vs baseline: 1.0858x; 1.0858x over previous
//
#include <hip/hip_runtime.h>

#define D_MODEL 2048
#define SEQ     2048
#define BATCH   4
#define MTOT    (BATCH * SEQ)   // 8192
#define NQKV    (3 * D_MODEL)   // 6144

typedef __attribute__((ext_vector_type(8))) short bf16x8;
typedef __attribute__((ext_vector_type(8))) unsigned short ushort8;
typedef __attribute__((ext_vector_type(4))) float floatx4;

__device__ __forceinline__ unsigned short f2b(float f) {
    unsigned x = __builtin_bit_cast(unsigned, f);
    x += 0x7fffu + ((x >> 16) & 1u);   // round-to-nearest-even
    return (unsigned short)(x >> 16);
}

__device__ __forceinline__ void storeC(float* p, float v) { *p = v; }
__device__ __forceinline__ void storeC(unsigned short* p, float v) { *p = f2b(v); }

__device__ __forceinline__ void gload_lds16(const void* g, void* l) {
    __builtin_amdgcn_global_load_lds(
        (const __attribute__((address_space(1))) void*)g,
        (__attribute__((address_space(3))) void*)l,
        16, 0, 0);
}

// ---------------------------------------------------------------------------
// 256x256 BT GEMM, 4-interval/K-tile FUSED schedule (z-batched):
// C[m,n] = sum_k A[m,k]*B[n,k] (+bias)(*scale). A,B bf16 k-major. BK=64,
// 8 waves (2M x 4N), per-wave C = 128x64.
// R3 post-mortem: 8 barriers/K-tile with reads, staging and MFMA in SEPARATE
// barrier intervals serializes the LDS pipe (890cy), MFMA pipe (2060cy), VALU
// (950cy) and barrier skew (~1200cy) -> 5300cy wall, MfmaUtil 42%. This
// version puts {frag ds_reads || staging gloads || 16 MFMA} in the SAME
// interval (compiler emits fine-grained lgkmcnt per consuming MFMA, m97
// style; NO forced lgkmcnt(0) drains) and halves barriers to 4/K-tile.
// Interval q computes C-quadrant q (2mi x 4ni x 2ks = 16 MFMA).
// Staging (1 granule = 64 LDS rows = 8KB = 1 gload/wave; 8/K-tile), placed
// >=1 barrier after the last read of the overwritten region:
//   I0: A1(kt+1) g0,g1 -> slot^1   [As[o][1] last read I3(kt-1)]
//   I1: B(kt+2) h0 g0,g1 -> slot   [Bs[s] last read I0(kt)]
//   I2: B(kt+2) h1 g0,g1 -> slot
//   I3: A0(kt+2) g0,g1 -> slot     [As[s][0] last read I1(kt)]
// Counted producer-side vmcnt (before the barrier; a wave's vmcnt covers its
// OWN loads, so the wait must precede the barrier that releases consumers):
//   steady: VMW(10) @I1-end (forces A1(kt), issued 5 intervals ago),
//           VMW(8)  @I3-end (forces B(kt+1)+A0(kt+1)).
//   tail kt=NK-2: VMW(8)/VMW(2); kt=NK-1: VMW(0)/none. Peak 14 in flight.
// Prologue: tile0 (8 gloads) + tile1 B,A0 (6 gloads), VMW(6), BAR.
// Requires NK even, NK >= 6 (all call sites: K=2048, NK=32).
// NOTE: default raster, no XCD swizzle (prior session: swizzle tripled FETCH).
// ---------------------------------------------------------------------------
#define BAR() do { asm volatile("" ::: "memory");                             \
                   __builtin_amdgcn_s_barrier();                              \
                   asm volatile("" ::: "memory"); } while (0)
#define VMW(N) asm volatile("s_waitcnt vmcnt(" #N ")" ::: "memory")

#define MFMA16(q)                                                             \
    __builtin_amdgcn_s_setprio(1);                                            \
    _Pragma("unroll") for (int ks = 0; ks < 2; ++ks)                          \
    _Pragma("unroll") for (int mi = 0; mi < 2; ++mi)                          \
    _Pragma("unroll") for (int ni = 0; ni < 4; ++ni)                          \
        acc[(q) * 2 + mi][ni] = __builtin_amdgcn_mfma_f32_16x16x32_bf16(      \
            af[mi][ks], bf[ni][ks], acc[(q) * 2 + mi][ni], 0, 0, 0);          \
    __builtin_amdgcn_s_setprio(0);

// M: 0 = steady, 1 = tail1 (kt = NK-2), 2 = tail2 (kt = NK-1)
#define KTILE(KT, S, O, M)                                                    \
  {                                                                           \
    /* I0: q0 — all B frags + A q0; stage A1(kt+1) */                         \
    ldBF(S);                                                                  \
    ldAF(S, 0, 0);                                                            \
    if (M < 2) { stA((KT) + 1, 1, 0, O); stA((KT) + 1, 1, 1, O); }            \
    MFMA16(0)                                                                 \
    BAR();                                                                    \
    /* I1: q1; stage B(kt+2) h0 */                                            \
    ldAF(S, 0, 1);                                                            \
    if (M == 0) { stB((KT) + 2, 0, 0, S); stB((KT) + 2, 0, 1, S); }           \
    MFMA16(1)                                                                 \
    if (M == 0) { VMW(10); } else if (M == 1) { VMW(8); } else { VMW(0); }    \
    BAR();                                                                    \
    /* I2: q2; stage B(kt+2) h1 */                                            \
    ldAF(S, 1, 0);                                                            \
    if (M == 0) { stB((KT) + 2, 1, 0, S); stB((KT) + 2, 1, 1, S); }           \
    MFMA16(2)                                                                 \
    BAR();                                                                    \
    /* I3: q3; stage A0(kt+2) */                                              \
    ldAF(S, 1, 1);                                                            \
    if (M == 0) { stA((KT) + 2, 0, 0, S); stA((KT) + 2, 0, 1, S); }           \
    MFMA16(3)                                                                 \
    if (M == 0) { VMW(8); } else if (M == 1) { VMW(2); }                      \
    if (M < 2) BAR();                                                         \
  }

template <int EPI, typename CT>
__global__ __launch_bounds__(512, 2) void gemm256(
    const unsigned short* __restrict__ A, int lda, long long strA,
    const unsigned short* __restrict__ B, int ldb, long long strB,
    CT* __restrict__ C, int ldc, long long strC,
    int K, const float* __restrict__ bias, float scale)
{
    // [slot][half][128 rows x 64 k] each; 64 KiB A + 64 KiB B = 128 KiB
    __shared__ __align__(16) unsigned short As[2][2][128 * 64];
    __shared__ __align__(16) unsigned short Bs[2][2][128 * 64];

    const int t = threadIdx.x;
    const int w = t >> 6, l = t & 63;
    const int wg_m = w >> 2, wg_n = w & 3;       // 2 x 4 wave grid
    const int quad = l >> 4, r16 = l & 15, sw = l & 7;
    const int cA0 = (quad ^ sw) * 8;             // ks0 swizzled col (elems)
    const int cA1 = ((4 + quad) ^ sw) * 8;       // ks1

    const int bz = blockIdx.z;
    A += (long long)bz * strA;
    B += (long long)bz * strB;
    C += (long long)bz * strC;

    const long long tM = (long long)blockIdx.y * 256;
    const long long tN = (long long)blockIdx.x * 256;

    // staging: thread t -> granule row r0 = t>>3 (0..63), slot s = t&7.
    // LDS(r,s) holds global k-chunk s^(r&7) (involution swizzle).
    const int r0 = t >> 3;
    const int kx = ((t & 7) ^ (r0 & 7)) * 8;
    const unsigned short* gA = A + (tM + r0) * (long long)lda + kx;
    const unsigned short* gB = B + (tN + r0) * (long long)ldb + kx;

    // one granule (64 LDS rows) per call; wave w writes rows [w*8, w*8+8)
    // A half h: LDS[sl][h] row r <-> global row (r>>6)*128 + h*64 + (r&63)
    auto stA = [&](int kt, int h, int g, int sl) {
        gload_lds16(gA + (long long)(g * 128 + h * 64) * lda + kt * 64,
                    &As[sl][h][g * 4096 + w * 512]);
    };
    // B half h: LDS[sl][h] row r <-> global row h*128 + r
    auto stB = [&](int kt, int h, int g, int sl) {
        gload_lds16(gB + (long long)(h * 128 + g * 64) * ldb + kt * 64,
                    &Bs[sl][h][g * 4096 + w * 512]);
    };

    bf16x8 af[2][2], bf[4][2];
    auto ldAF = [&](int sl, int h, int rq) {
        const unsigned short* base = &As[sl][h][0];
#pragma unroll
        for (int mi = 0; mi < 2; ++mi) {
            const int r = (wg_m * 64 + rq * 32 + mi * 16 + r16) * 64;
            af[mi][0] = *(const bf16x8*)&base[r + cA0];
            af[mi][1] = *(const bf16x8*)&base[r + cA1];
        }
    };
    auto ldBF = [&](int sl) {
        const unsigned short* base = &Bs[sl][wg_n >> 1][0];
#pragma unroll
        for (int ni = 0; ni < 4; ++ni) {
            const int r = ((wg_n & 1) * 64 + ni * 16 + r16) * 64;
            bf[ni][0] = *(const bf16x8*)&base[r + cA0];
            bf[ni][1] = *(const bf16x8*)&base[r + cA1];
        }
    };

    floatx4 acc[8][4];
#pragma unroll
    for (int i = 0; i < 8; ++i)
#pragma unroll
        for (int j = 0; j < 4; ++j)
            acc[i][j] = (floatx4){0.f, 0.f, 0.f, 0.f};

    const int NK = K >> 6;   // even, >= 6 at all call sites

    // prologue: tile 0 complete (8), then tile 1 B + A0 (6). A1(1) is staged
    // at I0(kt=0) per the steady schedule.
    stB(0, 0, 0, 0); stB(0, 0, 1, 0); stB(0, 1, 0, 0); stB(0, 1, 1, 0);
    stA(0, 0, 0, 0); stA(0, 0, 1, 0); stA(0, 1, 0, 0); stA(0, 1, 1, 0);
    stB(1, 0, 0, 1); stB(1, 0, 1, 1); stB(1, 1, 0, 1); stB(1, 1, 1, 1);
    stA(1, 0, 0, 1); stA(1, 0, 1, 1);
    VMW(6);                                   // MY tile-0 loads landed
    BAR();                                    // => ALL waves' tile-0 landed

    int kt = 0;
    for (; kt + 4 <= NK; kt += 2) {           // steady: kt = 0 .. NK-3
        KTILE(kt, 0, 1, 0)
        KTILE(kt + 1, 1, 0, 0)
    }
    KTILE(NK - 2, 0, 1, 1)                    // tail1
    KTILE(NK - 1, 1, 0, 2)                    // tail2 (no barrier after)

    // C/D layout: col = lane&15, row = (lane>>4)*4 + reg
#pragma unroll
    for (int mi = 0; mi < 8; ++mi) {
#pragma unroll
        for (int ni = 0; ni < 4; ++ni) {
            const long long row = tM + wg_m * 128 + mi * 16 + quad * 4;
            const int col = (int)tN + wg_n * 64 + ni * 16 + r16;
            float badd = 0.f;
            if (EPI == 0) badd = bias[col];
#pragma unroll
            for (int r = 0; r < 4; ++r) {
                float v = acc[mi][ni][r] + badd;
                if (EPI == 1) v *= scale;
                storeC(&C[(row + r) * ldc + col], v);
            }
        }
    }
}

// f32 -> bf16 bulk convert, 8 elems/thread (n divisible by 2048)
__global__ void cvt_f32_bf16(const float* __restrict__ in,
                             unsigned short* __restrict__ out, long long n)
{
    long long i = ((long long)blockIdx.x * 256 + threadIdx.x) * 8;
    if (i + 7 < n) {
        float4 a = *(const float4*)(in + i);
        float4 b = *(const float4*)(in + i + 4);
        ushort8 o = {f2b(a.x), f2b(a.y), f2b(a.z), f2b(a.w),
                     f2b(b.x), f2b(b.y), f2b(b.z), f2b(b.w)};
        *(ushort8*)(out + i) = o;
    }
}

// W_qkv f32 [2048, 6144] (f = 3*d + sel fastest) -> Wqkv_t bf16 [6144, 2048],
// Wqkv_t[sel*2048 + d][k] = W_qkv[k][3*d + sel].  Tile: 64 k x 32 d (96 cols).
__global__ void deint_wqkv(const float* __restrict__ W,
                           unsigned short* __restrict__ Wt)
{
    __shared__ unsigned short t2[96][72];   // row stride 144B (16B-aligned)
    const int d0 = blockIdx.x * 32;
    const int k0 = blockIdx.y * 64;
    const int t = threadIdx.x;

#pragma unroll
    for (int it = 0; it < 24; ++it) {
        int i = t + it * 256;               // 0..6143 over 64 rows x 96 cols
        int r = i / 96, c = i - r * 96;
        t2[c][r] = f2b(W[(long long)(k0 + r) * NQKV + 3 * d0 + c]);
    }
    __syncthreads();

#pragma unroll
    for (int rnd = 0; rnd < 3; ++rnd) {
        int c  = (t >> 3) + rnd * 32;       // 0..95
        int kc = t & 7;
        int dx = c / 3, sel = c - 3 * dx;
        *(ushort8*)&Wt[(long long)(sel * 2048 + d0 + dx) * D_MODEL + k0 + kc * 8] =
            *(const ushort8*)&t2[c][kc * 8];
    }
}

// W_fc f32 [2048, 2048] -> Wfc_t bf16, Wfc_t[n][k] = W_fc[k][n]. Tile 64x64.
__global__ void transpose_wfc(const float* __restrict__ W,
                              unsigned short* __restrict__ Wt)
{
    __shared__ unsigned short t2[64][72];
    const int n0 = blockIdx.x * 64;
    const int k0 = blockIdx.y * 64;
    const int t = threadIdx.x;

#pragma unroll
    for (int it = 0; it < 16; ++it) {
        int i = t + it * 256;               // 64 rows x 64 cols
        int r = i >> 6, c = i & 63;
        t2[c][r] = f2b(W[(long long)(k0 + r) * D_MODEL + n0 + c]);
    }
    __syncthreads();

#pragma unroll
    for (int rnd = 0; rnd < 2; ++rnd) {
        int c  = (t >> 3) + rnd * 32;
        int kc = t & 7;
        *(ushort8*)&Wt[(long long)(n0 + c) * D_MODEL + k0 + kc * 8] =
            *(const ushort8*)&t2[c][kc * 8];
    }
}

// bias deinterleave (f32 -> f32): bias_qkv_t[sel*2048+d] = bqkv[3*d+sel]
__global__ void prep_bias(const float* __restrict__ bqkv,
                          const float* __restrict__ bfc,
                          float* __restrict__ bias_qkv_t,
                          float* __restrict__ bias_fc)
{
    int i = blockIdx.x * 256 + threadIdx.x;
    if (i < NQKV) {
        int sel = i >> 11, d = i & 2047;
        bias_qkv_t[i] = bqkv[3 * d + sel];
    } else if (i < NQKV + D_MODEL) {
        bias_fc[i - NQKV] = bfc[i - NQKV];
    }
}

extern "C" void kernel_launch(void* const* d_in, const int* in_sizes, int n_in,
                              void* d_out, int out_size, void* d_ws, size_t ws_size,
                              hipStream_t stream)
{
    (void)in_sizes; (void)n_in; (void)out_size;

    const float* x    = (const float*)d_in[0];
    const float* Wqkv = (const float*)d_in[1];
    const float* bqkv = (const float*)d_in[2];
    const float* Wfc  = (const float*)d_in[3];
    const float* bfc  = (const float*)d_in[4];
    float* out = (float*)d_out;

    char* ws = (char*)d_ws;
    size_t off = 0;
    auto alloc = [&](size_t bytes) {
        void* p = ws + off;
        off += (bytes + 255) & ~(size_t)255;
        return p;
    };

    const float scale = 0.02209708691207961f;  // 2048^-0.5
    const long long nx = (long long)MTOT * D_MODEL;  // 16.8M elems

    const size_t NEED_BATCHED = (size_t)(33554432ull + 8388608ull + 25165824ull
                                + 100663296ull + 33554432ull + 65536ull);

    if (ws_size >= NEED_BATCHED) {
        unsigned short* xb     = (unsigned short*)alloc((size_t)MTOT * D_MODEL * 2);
        unsigned short* Wfc_t  = (unsigned short*)alloc((size_t)D_MODEL * D_MODEL * 2);
        unsigned short* Wqkv_t = (unsigned short*)alloc((size_t)NQKV * D_MODEL * 2);
        unsigned short* QKV    = (unsigned short*)alloc((size_t)MTOT * NQKV * 2);
        unsigned short* S      = (unsigned short*)alloc((size_t)BATCH * SEQ * SEQ * 2);
        float* bias_qkv = (float*)alloc((size_t)NQKV * 4);
        float* bias_fc  = (float*)alloc((size_t)D_MODEL * 4);
        unsigned short* Abuf = xb;   // xb dead after stage 1

        cvt_f32_bf16<<<(int)(nx / 2048), 256, 0, stream>>>(x, xb, nx);
        deint_wqkv<<<dim3(64, 32), 256, 0, stream>>>(Wqkv, Wqkv_t);
        transpose_wfc<<<dim3(32, 32), 256, 0, stream>>>(Wfc, Wfc_t);
        prep_bias<<<32, 256, 0, stream>>>(bqkv, bfc, bias_qkv, bias_fc);

        const long long sQKV = (long long)SEQ * NQKV;
        const long long sS   = (long long)SEQ * SEQ;

        // 1) QKV = xb @ Wqkv_t^T + bias   [8192 x 6144]
        gemm256<0, unsigned short><<<dim3(NQKV / 256, MTOT / 256, 1), 512, 0, stream>>>(
            xb, D_MODEL, 0, Wqkv_t, D_MODEL, 0, QKV, NQKV, 0, D_MODEL, bias_qkv, 1.f);
        // 2) S_b = Q_b @ K_b^T * scale    z-batched [2048 x 2048] x4
        gemm256<1, unsigned short><<<dim3(SEQ / 256, SEQ / 256, BATCH), 512, 0, stream>>>(
            QKV, NQKV, sQKV, QKV + D_MODEL, NQKV, sQKV, S, SEQ, sS, D_MODEL, nullptr, scale);
        // 3) A_b = S_b @ V_b^T            z-batched [2048 x 2048] x4
        gemm256<2, unsigned short><<<dim3(SEQ / 256, SEQ / 256, BATCH), 512, 0, stream>>>(
            S, SEQ, sS, QKV + 2 * D_MODEL, NQKV, sQKV, Abuf, SEQ, sS, SEQ, nullptr, 1.f);
        // 4) out = A @ Wfc_t^T + bias_fc  [8192 x 2048] f32 out
        gemm256<0, float><<<dim3(D_MODEL / 256, MTOT / 256, 1), 512, 0, stream>>>(
            Abuf, SEQ, 0, Wfc_t, D_MODEL, 0, out, D_MODEL, 0, SEQ, bias_fc, 1.f);
    } else {
        // Fallback: per-batch (~110 MB)
        unsigned short* xb     = (unsigned short*)alloc((size_t)MTOT * D_MODEL * 2);
        unsigned short* Wqkv_t = (unsigned short*)alloc((size_t)NQKV * D_MODEL * 2);
        unsigned short* Wfc_t  = (unsigned short*)alloc((size_t)D_MODEL * D_MODEL * 2);
        unsigned short* QKVb   = (unsigned short*)alloc((size_t)SEQ * NQKV * 2);
        unsigned short* Sb     = (unsigned short*)alloc((size_t)SEQ * SEQ * 2);
        unsigned short* Ab     = (unsigned short*)alloc((size_t)SEQ * SEQ * 2);
        float* bias_qkv = (float*)alloc((size_t)NQKV * 4);
        float* bias_fc  = (float*)alloc((size_t)D_MODEL * 4);

        cvt_f32_bf16<<<(int)(nx / 2048), 256, 0, stream>>>(x, xb, nx);
        deint_wqkv<<<dim3(64, 32), 256, 0, stream>>>(Wqkv, Wqkv_t);
        transpose_wfc<<<dim3(32, 32), 256, 0, stream>>>(Wfc, Wfc_t);
        prep_bias<<<32, 256, 0, stream>>>(bqkv, bfc, bias_qkv, bias_fc);

        for (int b = 0; b < BATCH; ++b) {
            const unsigned short* xb_b = xb + (long long)b * SEQ * D_MODEL;
            float* out_b = out + (long long)b * SEQ * D_MODEL;
            gemm256<0, unsigned short><<<dim3(NQKV / 256, SEQ / 256, 1), 512, 0, stream>>>(
                xb_b, D_MODEL, 0, Wqkv_t, D_MODEL, 0, QKVb, NQKV, 0, D_MODEL, bias_qkv, 1.f);
            gemm256<1, unsigned short><<<dim3(SEQ / 256, SEQ / 256, 1), 512, 0, stream>>>(
                QKVb, NQKV, 0, QKVb + D_MODEL, NQKV, 0, Sb, SEQ, 0, D_MODEL, nullptr, scale);
            gemm256<2, unsigned short><<<dim3(SEQ / 256, SEQ / 256, 1), 512, 0, stream>>>(
                Sb, SEQ, 0, QKVb + 2 * D_MODEL, NQKV, 0, Ab, SEQ, 0, SEQ, nullptr, 1.f);
            gemm256<0, float><<<dim3(D_MODEL / 256, SEQ / 256, 1), 512, 0, stream>>>(
                Ab, SEQ, 0, Wfc_t, D_MODEL, 0, out_b, D_MODEL, 0, SEQ, bias_fc, 1.f);
        }
    }
}